// Round 7
// baseline (74.318 us; speedup 1.0000x reference)
//
#include <hip/hip_runtime.h>
#include <math.h>

// Problem constants (match reference)
#define NF 256          // features
#define NB 64           // batch
#define M_CON 515       // 2N+3 constraints
static constexpr double EPS_Q  = 1e-4;
static constexpr double SIGMA  = 0.1;
static constexpr double CAPC   = 10.0;
static constexpr int    ITERS  = 20;

// Fast fp64 reciprocal: v_rcp_f64 seed + 1 NR step -> ~fp64 noise floor.
// Used for everything feeding the Newton direction (precision lesson: low-
// precision direction/state noise amplifies ~1/mu through the IPM residuals).
__device__ __forceinline__ double drcp(double x) {
    double r = __builtin_amdgcn_rcp(x);
    r = fma(r, fma(-x, r, 1.0), r);
    return r;
}
// Raw rcp (~2^-26 rel): ONLY for step-ratio denominators and alpha — enters
// the trajectory as a ~1e-8 relative step-length perturbation, benign
// (verified R5/R6: absmax stayed ~2e-7).
__device__ __forceinline__ double drcp_fast(double x) {
    return __builtin_amdgcn_rcp(x);
}

// DPP cross-lane for fp64: two 32-bit v_mov_b32 dpp + reassemble. VALU-speed.
template <int CTRL>
__device__ __forceinline__ double dpp_d(double v) {
    const int lo = __builtin_amdgcn_update_dpp(0, __double2loint(v), CTRL, 0xF, 0xF, true);
    const int hi = __builtin_amdgcn_update_dpp(0, __double2hiint(v), CTRL, 0xF, 0xF, true);
    return __hiloint2double(hi, lo);
}
__device__ __forceinline__ double bcast63(double v) {
    const int lo = __builtin_amdgcn_readlane(__double2loint(v), 63);
    const int hi = __builtin_amdgcn_readlane(__double2hiint(v), 63);
    return __hiloint2double(hi, lo);
}
// Wave64 sum: row_ror 1/2/4/8 (rotation-butterfly within 16-lane rows), then
// row_bcast15 + row_bcast31 accumulate row sums (bound_ctrl=1 injects 0 for
// invalid lanes); lane 63 holds the wave total, readlane -> uniform.
__device__ __forceinline__ double wave_red_sum(double v) {
    v += dpp_d<0x121>(v);   // row_ror:1
    v += dpp_d<0x122>(v);   // row_ror:2
    v += dpp_d<0x124>(v);   // row_ror:4
    v += dpp_d<0x128>(v);   // row_ror:8
    v += dpp_d<0x142>(v);   // row_bcast15
    v += dpp_d<0x143>(v);   // row_bcast31
    return bcast63(v);
}
// Same for max of nonnegative values (0-injection is safe).
__device__ __forceinline__ double wave_red_max_nn(double v) {
    v = fmax(v, dpp_d<0x121>(v));
    v = fmax(v, dpp_d<0x122>(v));
    v = fmax(v, dpp_d<0x124>(v));
    v = fmax(v, dpp_d<0x128>(v));
    v = fmax(v, dpp_d<0x142>(v));
    v = fmax(v, dpp_d<0x143>(v));
    return bcast63(v);
}

// 4 waves (256 threads) per batch item; thread t owns feature t.
// Was 1 wave/item (issue-bound at ~2600 cyc/iter on a single wave per CU);
// splitting 4x cuts per-wave issue work 4x, cross-wave reduce via LDS.
//
// Constraints: row0: sum(x)<=C ; lo_i: -x_i<=0 ; hi_i: x_i<=1 ;
// rowA: m.x <= rhs_fair+1 ; rowB: -m.x <= -rhs_fair.
// Exact-identity formulation (same fp64 trajectory as the 2.06e-7 R4 kernel):
//  * rs scales by (1-alpha); musum' = musum(1-a+a*sigma)+a^2*Sum(ds.dz)
//  * group1 reduce = {s11,s12,t1,t2}; Sdx/Smdx via identities;
//  * alpha = min(1, 0.99/max(rmax,0.99)), rmax = max(-ds/s, -dz/z);
//  * Schur M = D + d0*11^T + (dA+dB)*mm^T -> rank-2 Woodbury closed form.
__global__ __launch_bounds__(256)
void pdipm_kernel(const float* __restrict__ xin,
                  const int* __restrict__ male,
                  float* __restrict__ out) {
    const int b    = blockIdx.x;
    const int t    = threadIdx.x;      // 0..255 = feature index
    const int lane = t & 63;
    const int wv   = t >> 6;           // wave 0..3

    __shared__ double redA[4][4];      // group1: {s11,s12,t1,t2} per wave
    __shared__ double redB[4][2];      // group2: {dsdz, rmax} per wave
    // Buffer-reuse safety: the barrier of the OTHER group sits between any
    // read of a buffer and its next write (checked per-iteration ordering).

    // Per-thread (per-feature) state.
    double e, mfd, x, s_lo, s_hi, z_lo, z_hi, rs_lo, rs_hi;
    e   = (double)xin[b * NF + t];     // e = -(EPS*x + p), x=0, p=-xin
    mfd = (double)male[t];
    x = 0.0;
    s_lo = 1.0; s_hi = 1.0; z_lo = 1.0; z_hi = 1.0;
    rs_lo = 1.0; rs_hi = 0.0;

    // nm = sum(m) across block
    {
        const double nm_w = wave_red_sum(mfd);
        if (lane == 63) redA[wv][0] = nm_w;
        __syncthreads();
    }
    const double nm = redA[0][0] + redA[1][0] + redA[2][0] + redA[3][0];
    __syncthreads();                   // all reads done before iter-0 write
    const double rhs_fair = CAPC * nm * (1.0 / 256.0);

    // Scalar-constraint state (block-uniform, duplicated in every thread).
    double s0 = 1.0, z0 = 1.0, sA = 1.0, zA = 1.0, sB = 1.0, zB = 1.0;
    double rs0 = 1.0 - CAPC;
    double rsA = -rhs_fair;
    double rsB = 1.0 + rhs_fair;
    double musum = (double)M_CON;

    for (int it = 0; it < ITERS; ++it) {
        const double smu = SIGMA * musum * (1.0 / (double)M_CON);

        // ---- uniform scalar precompute (duplicated; hides under group1) ----
        const double i_s0 = drcp(s0), i_sA = drcp(sA), i_sB = drcp(sB);
        const double i_z0 = drcp_fast(z0), i_zA = drcp_fast(zA), i_zB = drcp_fast(zB);
        const double d0 = z0 * i_s0, dA = zA * i_sA, dB = zB * i_sB;
        const double beta  = d0 * rs0 + smu * i_s0;
        const double gamma = (dA * rsA + smu * i_sA) - (dB * rsB + smu * i_sB);
        const double ia  = drcp(d0);
        const double ibb = drcp(dA + dB);

        // ---- per-feature: d, invD, y; group1 partials ----
        const double i_sl = drcp(s_lo);
        const double i_sh = drcp(s_hi);
        const double i_zl = drcp_fast(z_lo);   // ratio-only
        const double i_zh = drcp_fast(z_hi);
        const double dl = z_lo * i_sl;
        const double dh = z_hi * i_sh;
        const double invD = drcp(EPS_Q + dl + dh);
        const double rhat = e + dl * rs_lo - dh * rs_hi + smu * (i_sl - i_sh);
        const double y = rhat * invD;

        const double r0 = wave_red_sum(invD);
        const double r1 = wave_red_sum(mfd * invD);
        const double r2 = wave_red_sum(y);
        const double r3 = wave_red_sum(mfd * y);
        if (lane == 63) {
            redA[wv][0] = r0; redA[wv][1] = r1;
            redA[wv][2] = r2; redA[wv][3] = r3;
        }
        __syncthreads();
        const double s11 = redA[0][0] + redA[1][0] + redA[2][0] + redA[3][0];
        const double s12 = redA[0][1] + redA[1][1] + redA[2][1] + redA[3][1];
        const double t1  = redA[0][2] + redA[1][2] + redA[2][2] + redA[3][2];
        const double t2  = redA[0][3] + redA[1][3] + redA[2][3] + redA[3][3];

        // ---- 2x2 capacitance algebra (closed-form M^-1 1 / M^-1 m) ----
        const double k11 = ia + s11;
        const double k22 = ibb + s12;
        const double i_det = drcp(k11 * k22 - s12 * s12);
        const double c1 = (k22 * t1 - s12 * t2) * i_det;
        const double c2 = (k11 * t2 - s12 * t1) * i_det;
        const double a1 =  ia * k22 * i_det;
        const double a2 = -ia * s12 * i_det;
        const double b1 = -ibb * s12 * i_det;
        const double b2 =  ibb * k11 * i_det;
        const double C1 = c1 + beta * a1 + gamma * b1;
        const double C2 = c2 + beta * a2 + gamma * b2;
        const double C1pC2 = C1 + C2;

        // ---- Sdx/Smdx via identities (no reduction) ----
        const double Sdx  = t1 - C1 * s11 - C2 * s12;
        const double Smdx = t2 - C1pC2 * s12;
        const double ds0 = -rs0 - Sdx;
        const double dsA = -rsA - Smdx;
        const double dsB = -rsB + Smdx;
        const double dz0 = smu * i_s0 - z0 - d0 * ds0;
        const double dzA = smu * i_sA - zA - dA * dsA;
        const double dzB = smu * i_sB - zB - dB * dsB;

        // ---- per-feature directions; group2 partials {dsdz, rmax} ----
        const double C12 = (mfd != 0.0) ? C1pC2 : C1;
        const double dx = fma(-invD, C12, y);
        const double ds_l = dx - rs_lo;        // ds = -rs - G dx, (G dx)_lo = -dx
        const double ds_h = -dx - rs_hi;
        const double dz_l = smu * i_sl - z_lo - dl * ds_l;
        const double dz_h = smu * i_sh - z_hi - dh * ds_h;
        const double dsdz_p = ds_l * dz_l + ds_h * dz_h;
        double rmax_p = fmax(fmax(-ds_l * i_sl, -ds_h * i_sh),
                             fmax(-dz_l * i_zl, -dz_h * i_zh));

        const double q0 = wave_red_sum(dsdz_p);
        const double q1 = wave_red_max_nn(rmax_p);
        if (lane == 63) { redB[wv][0] = q0; redB[wv][1] = q1; }
        __syncthreads();
        const double Sdsdz_f = redB[0][0] + redB[1][0] + redB[2][0] + redB[3][0];
        double rmax = fmax(fmax(redB[0][1], redB[1][1]),
                           fmax(redB[2][1], redB[3][1]));

        // scalar-constraint ratios (uniform)
        rmax = fmax(rmax, fmax(-ds0 * i_s0, -dz0 * i_z0));
        rmax = fmax(rmax, fmax(-dsA * i_sA, -dzA * i_zA));
        rmax = fmax(rmax, fmax(-dsB * i_sB, -dzB * i_zB));
        const double Sdsdz = Sdsdz_f + ds0 * dz0 + dsA * dzA + dsB * dzB;

        const double alpha = fmin(1.0, 0.99 * drcp_fast(fmax(rmax, 0.99)));
        const double omA = 1.0 - alpha;

        // ---- state update (identities keep rs/musum exact) ----
        const double adx = alpha * dx;
        x += adx;
        e = fma(-EPS_Q, adx, e);
        s_lo = fma(alpha, ds_l, s_lo);
        s_hi = fma(alpha, ds_h, s_hi);
        z_lo = fma(alpha, dz_l, z_lo);
        z_hi = fma(alpha, dz_h, z_hi);
        rs_lo *= omA;
        rs_hi *= omA;
        s0 = fma(alpha, ds0, s0); z0 = fma(alpha, dz0, z0);
        sA = fma(alpha, dsA, sA); zA = fma(alpha, dzA, zA);
        sB = fma(alpha, dsB, sB); zB = fma(alpha, dzB, zB);
        rs0 *= omA; rsA *= omA; rsB *= omA;
        musum = musum * (1.0 - alpha * (1.0 - SIGMA)) + alpha * alpha * Sdsdz;
    }

    out[b * NF + t] = (float)x;
}

extern "C" void kernel_launch(void* const* d_in, const int* in_sizes, int n_in,
                              void* d_out, int out_size, void* d_ws, size_t ws_size,
                              hipStream_t stream) {
    const float* xin  = (const float*)d_in[0];   // [64, 256] fp32
    const int*   male = (const int*)d_in[1];     // [256] int32
    float* out = (float*)d_out;                  // [64, 256] fp32
    pdipm_kernel<<<NB, 256, 0, stream>>>(xin, male, out);
}

// Round 8
// 73.512 us; speedup vs baseline: 1.0110x; 1.0110x over previous
//
#include <hip/hip_runtime.h>
#include <math.h>

// Problem constants (match reference)
#define NF 256          // features
#define NB 64           // batch
#define M_CON 515       // 2N+3 constraints
static constexpr double EPS_Q  = 1e-4;
static constexpr double SIGMA  = 0.1;
static constexpr double CAPC   = 10.0;
static constexpr int    ITERS  = 20;

// Fast fp64 reciprocal: v_rcp_f64 seed + 1 NR step -> ~fp64 noise floor.
// Used for everything feeding the Newton direction.
__device__ __forceinline__ double drcp(double x) {
    double r = __builtin_amdgcn_rcp(x);
    r = fma(r, fma(-x, r, 1.0), r);
    return r;
}
// Raw rcp (~2^-26 rel): ONLY step-ratio denominators / alpha (benign,
// verified R5-R7: absmax stayed ~2e-7).
__device__ __forceinline__ double drcp_fast(double x) {
    return __builtin_amdgcn_rcp(x);
}

// DPP cross-lane for fp64: two 32-bit v_mov_b32 dpp + reassemble. VALU-speed.
template <int CTRL>
__device__ __forceinline__ double dpp_d(double v) {
    const int lo = __builtin_amdgcn_update_dpp(0, __double2loint(v), CTRL, 0xF, 0xF, true);
    const int hi = __builtin_amdgcn_update_dpp(0, __double2hiint(v), CTRL, 0xF, 0xF, true);
    return __hiloint2double(hi, lo);
}
__device__ __forceinline__ double bcast63(double v) {
    const int lo = __builtin_amdgcn_readlane(__double2loint(v), 63);
    const int hi = __builtin_amdgcn_readlane(__double2hiint(v), 63);
    return __hiloint2double(hi, lo);
}
// Wave64 sum: row_ror 1/2/4/8 rotation-butterfly, then row_bcast15/31
// accumulate row sums (bound_ctrl=1 injects 0); lane 63 holds the total.
__device__ __forceinline__ double wave_red_sum(double v) {
    v += dpp_d<0x121>(v);   // row_ror:1
    v += dpp_d<0x122>(v);   // row_ror:2
    v += dpp_d<0x124>(v);   // row_ror:4
    v += dpp_d<0x128>(v);   // row_ror:8
    v += dpp_d<0x142>(v);   // row_bcast15
    v += dpp_d<0x143>(v);   // row_bcast31
    return bcast63(v);
}
// Max of nonnegative values (0-injection safe).
__device__ __forceinline__ double wave_red_max_nn(double v) {
    v = fmax(v, dpp_d<0x121>(v));
    v = fmax(v, dpp_d<0x122>(v));
    v = fmax(v, dpp_d<0x124>(v));
    v = fmax(v, dpp_d<0x128>(v));
    v = fmax(v, dpp_d<0x142>(v));
    v = fmax(v, dpp_d<0x143>(v));
    return bcast63(v);
}

// One wave per batch item (R7 showed 4-wave split is latency-neutral: chain
// bound, not issue bound). Lane j owns features j, j+64, j+128, j+192.
// Constraints: row0: sum(x)<=C ; lo_i: -x_i<=0 ; hi_i: x_i<=1 ;
// rowA: m.x <= rhs_fair+1 ; rowB: -m.x <= -rhs_fair.
//
// Exact-identity formulation (fp64 trajectory == the 2.06e-7 R4 kernel):
//  * rs scales by (1-alpha); musum' = musum(1-a+a*sigma)+a^2*Sum(ds.dz)
//  * group1 reduce = {s11,s12,t1,t2}; Sdx/Smdx via identities
//  * alpha = min(1, 0.99/max(rmax,0.99)), rmax = max(-ds/s, -dz/z)
//  * Schur M = D + d0*11^T + (dA+dB)*mm^T -> rank-2 Woodbury closed form
// R8 chain cuts (exact algebra): single-rcp y/invD via denom = EPS*sl*sh +
// zl*sh + zh*sl (all-positive); g = smu/s - z precomputed off-path; scalar
// ratios folded pre-reduce (max idempotent; dsdz on lane 0 only).
__global__ __launch_bounds__(64)
void pdipm_kernel(const float* __restrict__ xin,
                  const int* __restrict__ male,
                  float* __restrict__ out) {
    const int b = blockIdx.x;
    const int lane = threadIdx.x;

    double e[4], mf[4], x[4];                 // e = -(EPS*x + p) tracked
    double s_lo[4], s_hi[4], z_lo[4], z_hi[4];
    double rs_lo[4], rs_hi[4];
    double msum_p = 0.0;
    #pragma unroll
    for (int k = 0; k < 4; ++k) {
        const int f = lane + 64 * k;
        e[k]  = (double)xin[b * NF + f];       // e = -(EPS*0 + p) = -p = xin
        mf[k] = (double)male[f];
        msum_p += mf[k];
        x[k] = 0.0;
        s_lo[k] = 1.0; s_hi[k] = 1.0;
        z_lo[k] = 1.0; z_hi[k] = 1.0;
        rs_lo[k] = 1.0;                        // s - x
        rs_hi[k] = 0.0;                        // s + x - 1
    }
    const double nm = wave_red_sum(msum_p);
    const double rhs_fair = CAPC * nm * (1.0 / 256.0);

    // Scalar-constraint state (wave-uniform).
    double s0 = 1.0, z0 = 1.0, sA = 1.0, zA = 1.0, sB = 1.0, zB = 1.0;
    double rs0 = 1.0 - CAPC;
    double rsA = -rhs_fair;
    double rsB = 1.0 + rhs_fair;
    double musum = (double)M_CON;

    for (int it = 0; it < ITERS; ++it) {
        const double smu = SIGMA * musum * (1.0 / (double)M_CON);

        // ---- uniform scalar precompute (off critical path) ----
        const double i_s0 = drcp(s0), i_sA = drcp(sA), i_sB = drcp(sB);
        const double i_z0 = drcp_fast(z0), i_zA = drcp_fast(zA), i_zB = drcp_fast(zB);
        const double d0 = z0 * i_s0, dA = zA * i_sA, dB = zB * i_sB;
        const double beta  = d0 * rs0 + smu * i_s0;
        const double gamma = (dA * rsA + smu * i_sA) - (dB * rsB + smu * i_sB);
        const double ia  = drcp(d0);
        const double ibb = drcp(dA + dB);
        const double g0 = fma(smu, i_s0, -z0);
        const double gA = fma(smu, i_sA, -zA);
        const double gB = fma(smu, i_sB, -zB);

        // ---- group 1: single-rcp y/invD; partials in 2-deep trees ----
        double invD[4], y[4], i_sl[4], i_sh[4], i_zl[4], i_zh[4];
        double dl[4], dh[4], gl[4], gh[4];
        #pragma unroll
        for (int k = 0; k < 4; ++k) {
            const double prod  = s_lo[k] * s_hi[k];
            const double denom = fma(EPS_Q, prod,
                                     fma(z_lo[k], s_hi[k], z_hi[k] * s_lo[k]));
            const double R = drcp(denom);
            invD[k] = prod * R;
            const double Nr = fma(e[k], prod,
                              fma(z_lo[k] * rs_lo[k], s_hi[k],
                              fma(-(z_hi[k] * rs_hi[k]), s_lo[k],
                                  smu * (s_hi[k] - s_lo[k]))));
            y[k] = Nr * R;
            // off-path (consumed after reduce1; hides under DPP latency)
            i_sl[k] = drcp(s_lo[k]);
            i_sh[k] = drcp(s_hi[k]);
            i_zl[k] = drcp_fast(z_lo[k]);
            i_zh[k] = drcp_fast(z_hi[k]);
            dl[k] = z_lo[k] * i_sl[k];
            dh[k] = z_hi[k] * i_sh[k];
            gl[k] = fma(smu, i_sl[k], -z_lo[k]);
            gh[k] = fma(smu, i_sh[k], -z_hi[k]);
        }
        const double s11 = wave_red_sum((invD[0] + invD[1]) + (invD[2] + invD[3]));
        const double s12 = wave_red_sum((mf[0] * invD[0] + mf[1] * invD[1])
                                      + (mf[2] * invD[2] + mf[3] * invD[3]));
        const double t1  = wave_red_sum((y[0] + y[1]) + (y[2] + y[3]));
        const double t2  = wave_red_sum((mf[0] * y[0] + mf[1] * y[1])
                                      + (mf[2] * y[2] + mf[3] * y[3]));

        // ---- 2x2 capacitance algebra (closed-form M^-1 1 / M^-1 m) ----
        const double k11 = ia + s11;
        const double k22 = ibb + s12;
        const double i_det = drcp(k11 * k22 - s12 * s12);
        const double c1 = (k22 * t1 - s12 * t2) * i_det;
        const double c2 = (k11 * t2 - s12 * t1) * i_det;
        const double a1 =  ia * k22 * i_det;
        const double a2 = -ia * s12 * i_det;
        const double b1 = -ibb * s12 * i_det;
        const double b2 =  ibb * k11 * i_det;
        const double C1 = c1 + beta * a1 + gamma * b1;
        const double C2 = c2 + beta * a2 + gamma * b2;
        const double C1pC2 = C1 + C2;

        // ---- Sdx/Smdx via identities; scalar directions ----
        const double Sdx  = t1 - C1 * s11 - C2 * s12;
        const double Smdx = t2 - C1pC2 * s12;
        const double ds0 = -rs0 - Sdx;
        const double dsA = -rsA - Smdx;
        const double dsB = -rsB + Smdx;
        const double dz0 = fma(-d0, ds0, g0);
        const double dzA = fma(-dA, dsA, gA);
        const double dzB = fma(-dB, dsB, gB);

        // ---- group 2: directions; {Sdsdz, rmax} with scalars pre-folded ----
        double rmax_p = fmax(fmax(-ds0 * i_s0, -dz0 * i_z0),
                       fmax(fmax(-dsA * i_sA, -dzA * i_zA),
                            fmax(-dsB * i_sB, -dzB * i_zB)));
        rmax_p = fmax(rmax_p, 0.0);
        const double dsdz_scal = ds0 * dz0 + dsA * dzA + dsB * dzB;
        double dsdz_p = (lane == 0) ? dsdz_scal : 0.0;
        double dx[4], ds_l[4], ds_h[4], dz_l[4], dz_h[4];
        #pragma unroll
        for (int k = 0; k < 4; ++k) {
            const double C12 = (mf[k] != 0.0) ? C1pC2 : C1;
            dx[k] = fma(-invD[k], C12, y[k]);
            ds_l[k] = dx[k] - rs_lo[k];        // ds = -rs - G dx, (G dx)_lo = -dx
            ds_h[k] = -dx[k] - rs_hi[k];
            dz_l[k] = fma(-dl[k], ds_l[k], gl[k]);
            dz_h[k] = fma(-dh[k], ds_h[k], gh[k]);
            dsdz_p += ds_l[k] * dz_l[k] + ds_h[k] * dz_h[k];
            rmax_p = fmax(rmax_p,
                     fmax(fmax(-ds_l[k] * i_sl[k], -ds_h[k] * i_sh[k]),
                          fmax(-dz_l[k] * i_zl[k], -dz_h[k] * i_zh[k])));
        }
        const double Sdsdz = wave_red_sum(dsdz_p);
        const double rmax  = wave_red_max_nn(rmax_p);

        const double alpha = fmin(1.0, 0.99 * drcp_fast(fmax(rmax, 0.99)));
        const double omA = 1.0 - alpha;

        // ---- state update (identities keep rs/musum exact) ----
        #pragma unroll
        for (int k = 0; k < 4; ++k) {
            const double adx = alpha * dx[k];
            x[k] += adx;
            e[k] = fma(-EPS_Q, adx, e[k]);
            s_lo[k] = fma(alpha, ds_l[k], s_lo[k]);
            s_hi[k] = fma(alpha, ds_h[k], s_hi[k]);
            z_lo[k] = fma(alpha, dz_l[k], z_lo[k]);
            z_hi[k] = fma(alpha, dz_h[k], z_hi[k]);
            rs_lo[k] *= omA;
            rs_hi[k] *= omA;
        }
        s0 = fma(alpha, ds0, s0); z0 = fma(alpha, dz0, z0);
        sA = fma(alpha, dsA, sA); zA = fma(alpha, dzA, zA);
        sB = fma(alpha, dsB, sB); zB = fma(alpha, dzB, zB);
        rs0 *= omA; rsA *= omA; rsB *= omA;
        musum = musum * (1.0 - alpha * (1.0 - SIGMA)) + alpha * alpha * Sdsdz;
    }

    #pragma unroll
    for (int k = 0; k < 4; ++k)
        out[b * NF + lane + 64 * k] = (float)x[k];
}

extern "C" void kernel_launch(void* const* d_in, const int* in_sizes, int n_in,
                              void* d_out, int out_size, void* d_ws, size_t ws_size,
                              hipStream_t stream) {
    const float* xin  = (const float*)d_in[0];   // [64, 256] fp32
    const int*   male = (const int*)d_in[1];     // [256] int32
    float* out = (float*)d_out;                  // [64, 256] fp32
    pdipm_kernel<<<NB, 64, 0, stream>>>(xin, male, out);
}